// Round 1
// 2161.785 us; speedup vs baseline: 1.8905x; 1.8905x over previous
//
#include <hip/hip_runtime.h>
#include <hip/hip_bf16.h>
#include <math.h>

// ROUND 8: GEMMs -> MFMA split-bf16 (3-product). Pipeline numerics designed
// to match the r7 fp32 oracle: a = a_hi + a_lo (truncation split, exact),
// C ~= Ah*Wh + Ah*Wl + Al*Wh (dropped Al*Wl ~ 2^-16 relative). attn_naive
// and ln_gate unchanged (attn is next round's target).
// Established: inputs fp32, output fp32, ws_size >= 40 MiB.
// ws: [0,16M) q fp32 -> y in-place; [16,32M) k fp32 -> a (reuse);
// [32,40M) v bf16. g bf16 staged in d_out[0,8M), dead before final GEMM
// overwrites d_out with 16 MiB fp32.

typedef __bf16 bf16;
typedef unsigned short u16;
typedef __attribute__((ext_vector_type(4))) float f32x4;
typedef __attribute__((ext_vector_type(8))) short short8;
typedef __attribute__((ext_vector_type(4))) short short4v;

#define S_ 2048
#define D_ 2048
#define H_ 16
#define HD_ 128
#define SCALE_ 0.08838834764831843f   // 128^-0.5

union BU { bf16 b; u16 u; };

__device__ __forceinline__ u16 bfbits(float f) { BU x; x.b = (bf16)f; return x.u; }

__device__ __forceinline__ bool is_f32(const void* p) {
  const u16* xr = (const u16*)p;
  int cnt = 0;
  for (int i = 0; i < 128; ++i) {
    int e = (xr[2 * i] >> 7) & 0xFF;
    cnt += (e >= 100 && e <= 140) ? 1 : 0;
  }
  return cnt < 96;
}

// ---------------------------------------------------------------------------
// MFMA GEMM: C(2048,2048) = A @ W^T (+optional SiLU), A,W fp32 row-major,
// W is (N,K). Split-bf16 3-product for near-fp32 accuracy.
// 128x128 tile, BK=32, 256 thr / 4 waves, each wave 64x64 = 4x4 frags of
// mfma_f32_16x16x32_bf16. LDS stride 40 (pad 8) -> conflict-free b128 reads.
// Double-buffered, 1 barrier/K-step, loads issued early (T14).
// ---------------------------------------------------------------------------
__device__ __forceinline__ void load_tiles(const float* __restrict__ A,
    const float* __restrict__ W, int r0, int c0, int ko, int srow, int sch,
    f32x4* ra, f32x4* rw) {
#pragma unroll
  for (int n = 0; n < 4; ++n) {
    ra[n] = *(const f32x4*)(A + (size_t)(r0 + srow + 32 * n) * D_ + ko + sch);
    rw[n] = *(const f32x4*)(W + (size_t)(c0 + srow + 32 * n) * D_ + ko + sch);
  }
}

__device__ __forceinline__ void split_write(u16 (* __restrict__ dh)[40],
    u16 (* __restrict__ dl)[40], const f32x4* r, int srow, int sch) {
#pragma unroll
  for (int n = 0; n < 4; ++n) {
    short4v h, l;
#pragma unroll
    for (int e = 0; e < 4; ++e) {
      float f = r[n][e];
      unsigned int bits = __float_as_uint(f);
      u16 hb = (u16)(bits >> 16);                       // truncation split
      float hf = __uint_as_float(bits & 0xFFFF0000u);   // exact
      h[e] = (short)hb;
      l[e] = (short)bfbits(f - hf);                     // RNE residual
    }
    *(short4v*)&dh[srow + 32 * n][sch] = h;
    *(short4v*)&dl[srow + 32 * n][sch] = l;
  }
}

__global__ __launch_bounds__(256, 1) void gemm_mfma(
    const float* __restrict__ A, const float* __restrict__ W,
    void* __restrict__ Cv, int silu, int c_bf16) {
  __shared__ __align__(16) u16 sAh[2][128][40];
  __shared__ __align__(16) u16 sAl[2][128][40];
  __shared__ __align__(16) u16 sWh[2][128][40];
  __shared__ __align__(16) u16 sWl[2][128][40];

  const int t = threadIdx.x;
  const int lane = t & 63;
  const int wv = t >> 6;
  const int wr = (wv >> 1) * 64;   // wave row offset in tile
  const int wc = (wv & 1) * 64;    // wave col offset in tile
  const int r0 = blockIdx.y * 128;
  const int c0 = blockIdx.x * 128;

  const int srow = t >> 3;         // staging row 0..31 (+32n)
  const int sch = (t & 7) * 4;     // staging k-chunk (4 floats)

  const int l15 = lane & 15;
  const int kq = (lane >> 4) * 8;  // frag k offset (elements)

  f32x4 ra[4], rw[4];
  f32x4 acc[4][4];
#pragma unroll
  for (int i = 0; i < 4; ++i)
#pragma unroll
    for (int j = 0; j < 4; ++j) acc[i][j] = (f32x4){0.f, 0.f, 0.f, 0.f};

  // prologue: stage tile 0
  load_tiles(A, W, r0, c0, 0, srow, sch, ra, rw);
  split_write(sAh[0], sAl[0], ra, srow, sch);
  split_write(sWh[0], sWl[0], rw, srow, sch);
  __syncthreads();

  for (int kt = 0; kt < D_ / 32; ++kt) {
    const int cur = kt & 1;
    const bool more = (kt + 1 < D_ / 32);
    if (more) load_tiles(A, W, r0, c0, (kt + 1) * 32, srow, sch, ra, rw);

    short8 fah[4], fal[4], fbh[4], fbl[4];
#pragma unroll
    for (int i = 0; i < 4; ++i) {
      fah[i] = *(const short8*)&sAh[cur][wr + i * 16 + l15][kq];
      fal[i] = *(const short8*)&sAl[cur][wr + i * 16 + l15][kq];
      fbh[i] = *(const short8*)&sWh[cur][wc + i * 16 + l15][kq];
      fbl[i] = *(const short8*)&sWl[cur][wc + i * 16 + l15][kq];
    }
#pragma unroll
    for (int i = 0; i < 4; ++i)
#pragma unroll
      for (int j = 0; j < 4; ++j) {
        acc[i][j] = __builtin_amdgcn_mfma_f32_16x16x32_bf16(fah[i], fbh[j], acc[i][j], 0, 0, 0);
        acc[i][j] = __builtin_amdgcn_mfma_f32_16x16x32_bf16(fah[i], fbl[j], acc[i][j], 0, 0, 0);
        acc[i][j] = __builtin_amdgcn_mfma_f32_16x16x32_bf16(fal[i], fbh[j], acc[i][j], 0, 0, 0);
      }
    if (more) {
      split_write(sAh[cur ^ 1], sAl[cur ^ 1], ra, srow, sch);
      split_write(sWh[cur ^ 1], sWl[cur ^ 1], rw, srow, sch);
    }
    __syncthreads();
  }

  // epilogue: C/D mapping col=lane&15, row=(lane>>4)*4+reg  [m89-verified]
  const int orow = (lane >> 4) * 4;
#pragma unroll
  for (int i = 0; i < 4; ++i)
#pragma unroll
    for (int j = 0; j < 4; ++j)
#pragma unroll
      for (int r = 0; r < 4; ++r) {
        float val = acc[i][j][r];
        if (silu) val = val / (1.f + expf(-val));
        size_t idx = (size_t)(r0 + wr + i * 16 + orow + r) * D_ +
                     (c0 + wc + j * 16 + l15);
        if (c_bf16) ((bf16*)Cv)[idx] = (bf16)val;
        else        ((float*)Cv)[idx] = val;
      }
}

// ---------------------------------------------------------------------------
// Naive attention (block = 32 i-rows x head). qy overwritten in-place by y.
// (unchanged from r7 — next round's target)
// ---------------------------------------------------------------------------
__global__ __launch_bounds__(256) void attn_naive(
    float* __restrict__ qy, const float* __restrict__ k,
    const bf16* __restrict__ v, const void* __restrict__ xs) {
  const int h = blockIdx.y;
  const int i0 = blockIdx.x * 32;
  const int t = threadIdx.x;

  __shared__ float qs[32][129];
  __shared__ float ks[32][129];
  __shared__ float vs[32][129];
  __shared__ float ss[32][33];

  const double l1 = -3.4657359027997265;
  const double l2 = -6.238324625039508;
  float gam = (float)(1.0 - exp(l1 + (double)h * ((l2 - l1) / 15.0)));
  if (!is_f32(xs)) gam = (float)(bf16)gam;
  const float log2g = log2f(gam);

#pragma unroll
  for (int n = 0; n < 16; ++n) {
    int e = t + 256 * n;
    int row = e >> 7, col = e & 127;
    qs[row][col] = qy[(size_t)(i0 + row) * D_ + h * HD_ + col];
  }

  const int il = t >> 3;
  const int jq = t & 7;
  float yacc[16] = {};

  for (int jt = 0; jt <= blockIdx.x; ++jt) {
    const int j0 = jt * 32;
    __syncthreads();
#pragma unroll
    for (int n = 0; n < 16; ++n) {
      int e = t + 256 * n;
      int row = e >> 7, col = e & 127;
      ks[row][col] = k[(size_t)(j0 + row) * D_ + h * HD_ + col];
      vs[row][col] = (float)v[(size_t)(j0 + row) * D_ + h * HD_ + col];
    }
    __syncthreads();

#pragma unroll
    for (int jj = 0; jj < 4; ++jj) {
      int jl = jq * 4 + jj;
      float dot = 0.f;
      for (int d = 0; d < 128; ++d) dot += qs[il][d] * ks[jl][d];
      int delta = (i0 + il) - (j0 + jl);
      float dec = (delta >= 0) ? exp2f((float)delta * log2g) : 0.f;
      ss[il][jl] = dot * SCALE_ * dec;
    }
    __syncthreads();

#pragma unroll
    for (int jl = 0; jl < 32; ++jl) {
      float sv = ss[il][jl];
#pragma unroll
      for (int dd = 0; dd < 16; ++dd) yacc[dd] += sv * vs[jl][jq + 8 * dd];
    }
  }

#pragma unroll
  for (int dd = 0; dd < 16; ++dd)
    qy[(size_t)(i0 + il) * D_ + h * HD_ + jq + 8 * dd] = yacc[dd];
}

// ---------------------------------------------------------------------------
__global__ __launch_bounds__(256) void ln_gate(const float* __restrict__ y,
                                               const bf16* __restrict__ g,
                                               const void* __restrict__ lnw,
                                               const void* __restrict__ lnb,
                                               float* __restrict__ a) {
  const int row = blockIdx.x;
  const int t = threadIdx.x;
  const bool lF = is_f32(lnw);
  const float* yr = y + (size_t)row * D_;

  float v[8], s = 0.f, s2 = 0.f;
#pragma unroll
  for (int e = 0; e < 8; ++e) {
    v[e] = yr[t + 256 * e];
    s += v[e];
    s2 += v[e] * v[e];
  }
#pragma unroll
  for (int off = 32; off > 0; off >>= 1) {
    s += __shfl_down(s, off);
    s2 += __shfl_down(s2, off);
  }
  __shared__ float red[8];
  __shared__ float mv[2];
  if ((t & 63) == 0) { red[(t >> 6) * 2] = s; red[(t >> 6) * 2 + 1] = s2; }
  __syncthreads();
  if (t == 0) {
    float S1 = red[0] + red[2] + red[4] + red[6];
    float S2 = red[1] + red[3] + red[5] + red[7];
    float mu = S1 * (1.f / (float)D_);
    float var = S2 * (1.f / (float)D_) - mu * mu;
    mv[0] = mu;
    mv[1] = rsqrtf(var + 1e-5f);
  }
  __syncthreads();
  float mu = mv[0], rstd = mv[1];
#pragma unroll
  for (int e = 0; e < 8; ++e) {
    int col = t + 256 * e;
    float lw = lF ? ((const float*)lnw)[col] : (float)((const bf16*)lnw)[col];
    float lb = lF ? ((const float*)lnb)[col] : (float)((const bf16*)lnb)[col];
    float val = (v[e] - mu) * rstd * lw + lb;
    float gg = (float)g[(size_t)row * D_ + col];
    a[(size_t)row * D_ + col] = val * gg;
  }
}

// ---------------------------------------------------------------------------
extern "C" void kernel_launch(void* const* d_in, const int* in_sizes, int n_in,
                              void* d_out, int out_size, void* d_ws, size_t ws_size,
                              hipStream_t stream) {
  const void* x   = d_in[0];
  const void* wq  = d_in[1];
  const void* wk  = d_in[2];
  const void* wv  = d_in[3];
  const void* wg  = d_in[4];
  const void* wo  = d_in[5];
  const void* lnw = d_in[6];
  const void* lnb = d_in[7];

  char* ws = (char*)d_ws;
  float* q  = (float*)(ws);                  // 16 MiB fp32; becomes y in-place
  float* kk = (float*)(ws + (16ull << 20));  // 16 MiB fp32; becomes a
  bf16*  v  = (bf16*)(ws + (32ull << 20));   // 8 MiB bf16
  float* a  = kk;
  bf16*  g  = (bf16*)d_out;                  // staged in d_out[0,8M), dead
                                             // before final fp32 overwrite
  float* out = (float*)d_out;                // OUTPUT IS FP32 (r6 probe)

  dim3 blk(256);
  dim3 gg(16, 16);
  gemm_mfma<<<gg, blk, 0, stream>>>((const float*)x, (const float*)wq, q,  0, 0);
  gemm_mfma<<<gg, blk, 0, stream>>>((const float*)x, (const float*)wk, kk, 0, 0);
  gemm_mfma<<<gg, blk, 0, stream>>>((const float*)x, (const float*)wv, v,  0, 1);
  gemm_mfma<<<gg, blk, 0, stream>>>((const float*)x, (const float*)wg, g,  1, 1);
  attn_naive<<<dim3(64, 16), blk, 0, stream>>>(q, kk, v, x);
  ln_gate<<<dim3(2048), blk, 0, stream>>>(q /*=y*/, g, lnw, lnb, a);
  gemm_mfma<<<gg, blk, 0, stream>>>(a, (const float*)wo, out, 0, 0);
}

// Round 2
// 827.420 us; speedup vs baseline: 4.9392x; 2.6127x over previous
//
#include <hip/hip_runtime.h>
#include <hip/hip_bf16.h>
#include <math.h>

// ROUND 9: attention -> MFMA split-bf16. Decay factorized into operand
// scales: q *= SCALE*gamma^(i-i0), k *= gamma^(i0-j)  =>  qk = score*decay
// with only the causal mask applied in the accumulator (diag tile).
// QK^T: 3-product split (hh+hl+lh). PV: scores split hi/lo x bf16 v
// (2-product). v now written TRANSPOSED vT[n][s] by the wv GEMM epilogue
// (packed 8B stores) so PV B-frags are contiguous b128 LDS reads.
// LDS frag layouts XOR-swizzled on 16B granules (bank-balanced b128).
// GEMM core unchanged from r8 (its limiter is HBM traffic -> next round).
// Established: inputs fp32, output fp32, ws >= 40 MiB.
// ws: [0,16M) q fp32 -> y in-place; [16,32M) k fp32 -> a (reuse);
// [32,40M) vT bf16. g bf16 staged in d_out[0,8M), dead before final GEMM.

typedef __bf16 bf16;
typedef unsigned short u16;
typedef __attribute__((ext_vector_type(4))) float f32x4;
typedef __attribute__((ext_vector_type(8))) short short8;
typedef __attribute__((ext_vector_type(4))) short short4v;

#define S_ 2048
#define D_ 2048
#define H_ 16
#define HD_ 128
#define SCALE_ 0.08838834764831843f   // 128^-0.5

union BU { bf16 b; u16 u; };

__device__ __forceinline__ u16 bfbits(float f) { BU x; x.b = (bf16)f; return x.u; }

__device__ __forceinline__ void split1(float f, u16& h, u16& l) {
  unsigned int bits = __float_as_uint(f);
  h = (u16)(bits >> 16);                          // truncation split (exact)
  float hf = __uint_as_float(bits & 0xFFFF0000u);
  l = bfbits(f - hf);                             // RNE residual
}

__device__ __forceinline__ bool is_f32(const void* p) {
  const u16* xr = (const u16*)p;
  int cnt = 0;
  for (int i = 0; i < 128; ++i) {
    int e = (xr[2 * i] >> 7) & 0xFF;
    cnt += (e >= 100 && e <= 140) ? 1 : 0;
  }
  return cnt < 96;
}

// ---------------------------------------------------------------------------
// MFMA GEMM (r8, unchanged core): C(2048,2048) = A @ W^T (+opt SiLU).
// vt_mode: write C transposed as bf16 vT[n][s] (packed 4-row 8B stores).
// ---------------------------------------------------------------------------
__device__ __forceinline__ void load_tiles(const float* __restrict__ A,
    const float* __restrict__ W, int r0, int c0, int ko, int srow, int sch,
    f32x4* ra, f32x4* rw) {
#pragma unroll
  for (int n = 0; n < 4; ++n) {
    ra[n] = *(const f32x4*)(A + (size_t)(r0 + srow + 32 * n) * D_ + ko + sch);
    rw[n] = *(const f32x4*)(W + (size_t)(c0 + srow + 32 * n) * D_ + ko + sch);
  }
}

__device__ __forceinline__ void split_write(u16 (* __restrict__ dh)[40],
    u16 (* __restrict__ dl)[40], const f32x4* r, int srow, int sch) {
#pragma unroll
  for (int n = 0; n < 4; ++n) {
    short4v h, l;
#pragma unroll
    for (int e = 0; e < 4; ++e) {
      u16 hb, lb;
      split1(r[n][e], hb, lb);
      h[e] = (short)hb;
      l[e] = (short)lb;
    }
    *(short4v*)&dh[srow + 32 * n][sch] = h;
    *(short4v*)&dl[srow + 32 * n][sch] = l;
  }
}

__global__ __launch_bounds__(256, 1) void gemm_mfma(
    const float* __restrict__ A, const float* __restrict__ W,
    void* __restrict__ Cv, int silu, int c_bf16, int vt_mode) {
  __shared__ __align__(16) u16 sAh[2][128][40];
  __shared__ __align__(16) u16 sAl[2][128][40];
  __shared__ __align__(16) u16 sWh[2][128][40];
  __shared__ __align__(16) u16 sWl[2][128][40];

  const int t = threadIdx.x;
  const int lane = t & 63;
  const int wv = t >> 6;
  const int wr = (wv >> 1) * 64;
  const int wc = (wv & 1) * 64;
  const int r0 = blockIdx.y * 128;
  const int c0 = blockIdx.x * 128;

  const int srow = t >> 3;
  const int sch = (t & 7) * 4;

  const int l15 = lane & 15;
  const int kq = (lane >> 4) * 8;

  f32x4 ra[4], rw[4];
  f32x4 acc[4][4];
#pragma unroll
  for (int i = 0; i < 4; ++i)
#pragma unroll
    for (int j = 0; j < 4; ++j) acc[i][j] = (f32x4){0.f, 0.f, 0.f, 0.f};

  load_tiles(A, W, r0, c0, 0, srow, sch, ra, rw);
  split_write(sAh[0], sAl[0], ra, srow, sch);
  split_write(sWh[0], sWl[0], rw, srow, sch);
  __syncthreads();

  for (int kt = 0; kt < D_ / 32; ++kt) {
    const int cur = kt & 1;
    const bool more = (kt + 1 < D_ / 32);
    if (more) load_tiles(A, W, r0, c0, (kt + 1) * 32, srow, sch, ra, rw);

    short8 fah[4], fal[4], fbh[4], fbl[4];
#pragma unroll
    for (int i = 0; i < 4; ++i) {
      fah[i] = *(const short8*)&sAh[cur][wr + i * 16 + l15][kq];
      fal[i] = *(const short8*)&sAl[cur][wr + i * 16 + l15][kq];
      fbh[i] = *(const short8*)&sWh[cur][wc + i * 16 + l15][kq];
      fbl[i] = *(const short8*)&sWl[cur][wc + i * 16 + l15][kq];
    }
#pragma unroll
    for (int i = 0; i < 4; ++i)
#pragma unroll
      for (int j = 0; j < 4; ++j) {
        acc[i][j] = __builtin_amdgcn_mfma_f32_16x16x32_bf16(fah[i], fbh[j], acc[i][j], 0, 0, 0);
        acc[i][j] = __builtin_amdgcn_mfma_f32_16x16x32_bf16(fah[i], fbl[j], acc[i][j], 0, 0, 0);
        acc[i][j] = __builtin_amdgcn_mfma_f32_16x16x32_bf16(fal[i], fbh[j], acc[i][j], 0, 0, 0);
      }
    if (more) {
      split_write(sAh[cur ^ 1], sAl[cur ^ 1], ra, srow, sch);
      split_write(sWh[cur ^ 1], sWl[cur ^ 1], rw, srow, sch);
    }
    __syncthreads();
  }

  const int orow = (lane >> 4) * 4;   // C/D: col=lane&15, row=(lane>>4)*4+r
  if (vt_mode) {
#pragma unroll
    for (int i = 0; i < 4; ++i)
#pragma unroll
      for (int j = 0; j < 4; ++j) {
        short4v p;
#pragma unroll
        for (int r = 0; r < 4; ++r) p[r] = (short)bfbits(acc[i][j][r]);
        size_t n  = (size_t)(c0 + wc + j * 16 + l15);
        size_t s0 = (size_t)(r0 + wr + i * 16 + orow);
        *(short4v*)((bf16*)Cv + n * (size_t)S_ + s0) = p;   // vT[n][s0..s0+3]
      }
  } else {
#pragma unroll
    for (int i = 0; i < 4; ++i)
#pragma unroll
      for (int j = 0; j < 4; ++j)
#pragma unroll
        for (int r = 0; r < 4; ++r) {
          float val = acc[i][j][r];
          if (silu) val = val / (1.f + expf(-val));
          size_t idx = (size_t)(r0 + wr + i * 16 + orow + r) * D_ +
                       (c0 + wc + j * 16 + l15);
          if (c_bf16) ((bf16*)Cv)[idx] = (bf16)val;
          else        ((float*)Cv)[idx] = val;
        }
  }
}

// ---------------------------------------------------------------------------
// MFMA retention attention. Block = (64-row i-tile, head), 4 waves x 16 rows.
// q A-frags in regs (scaled SCALE*gamma^(i-i0), split-bf16).
// Per j-tile: k staged split-bf16 scaled gamma^(i0-j); vT staged bf16.
// QK^T 3-product -> mask (diag) -> split -> wave-private scores LDS ->
// PV 2-product with vT B-frags. All frag LDS XOR-swizzled on 16B granules.
// y overwrites q in-place (reads all done in prologue).
// ---------------------------------------------------------------------------
__global__ __launch_bounds__(256, 2) void attn_mfma(
    float* __restrict__ qy, const float* __restrict__ k,
    const bf16* __restrict__ vt) {
  const int h = blockIdx.y;
  const int bxx = blockIdx.x;
  const int bx = (bxx & 1) ? (31 - (bxx >> 1)) : (bxx >> 1);  // pair long+short
  const int i0 = bx * 64;
  const int t = threadIdx.x;
  const int lane = t & 63;
  const int wv = t >> 6;
  const int l15 = lane & 15;
  const int hi = lane >> 4;

  __shared__ __align__(16) u16 skh[64][128];      // k hi, swz g^(row&15)
  __shared__ __align__(16) u16 skl[64][128];      // k lo
  __shared__ __align__(16) u16 svt[128][64];      // vT,  swz g^(row&7)
  __shared__ __align__(16) u16 ssc[4][2][16][64]; // scores per wave (hi,lo)

  const double l1 = -3.4657359027997265;          // log(1/32)
  const double l2 = -6.238324625039508;           // log(1/512)
  const float gam = (float)(1.0 - exp(l1 + (double)h * ((l2 - l1) / 15.0)));
  const float log2g = log2f(gam);

  // q fragments in registers: A layout row=lane&15, k=(lane>>4)*8+e
  short8 fqh[4], fql[4];
  {
    const float qs = SCALE_ * exp2f((float)(wv * 16 + l15) * log2g);
    const float* qrow = qy + (size_t)(i0 + wv * 16 + l15) * D_ + h * HD_;
#pragma unroll
    for (int ks = 0; ks < 4; ++ks) {
      f32x4 a = *(const f32x4*)(qrow + ks * 32 + hi * 8);
      f32x4 b = *(const f32x4*)(qrow + ks * 32 + hi * 8 + 4);
      short8 hh, ll;
#pragma unroll
      for (int e = 0; e < 8; ++e) {
        float f = (e < 4 ? a[e] : b[e - 4]) * qs;
        u16 hb, lb;
        split1(f, hb, lb);
        hh[e] = (short)hb;
        ll[e] = (short)lb;
      }
      fqh[ks] = hh;
      fql[ks] = ll;
    }
  }

  f32x4 yacc[8];
#pragma unroll
  for (int dt = 0; dt < 8; ++dt) yacc[dt] = (f32x4){0.f, 0.f, 0.f, 0.f};

  for (int jt = 0; jt <= bx; ++jt) {
    const int j0 = jt * 64;
    __syncthreads();   // prev iteration's frag reads done before restage

    // stage k: 64 rows x 128 d fp32 -> split bf16, scaled gamma^(i0-j)
#pragma unroll
    for (int n = 0; n < 8; ++n) {
      int id = t + 256 * n;            // 2048 chunks of 4 floats
      int row = id >> 5;               // 0..63
      int c4 = (id & 31) * 4;          // 0..124
      float ksc = exp2f((float)(i0 - j0 - row) * log2g);
      f32x4 kv = *(const f32x4*)(k + (size_t)(j0 + row) * D_ + h * HD_ + c4);
      short4v hh, ll;
#pragma unroll
      for (int e = 0; e < 4; ++e) {
        u16 hb, lb;
        split1(kv[e] * ksc, hb, lb);
        hh[e] = (short)hb;
        ll[e] = (short)lb;
      }
      int sw = (((c4 >> 3) ^ (row & 15)) << 3) + (c4 & 7);
      *(short4v*)&skh[row][sw] = hh;
      *(short4v*)&skl[row][sw] = ll;
    }
    // stage vT: 128 rows(d) x 64 cols(s) bf16
#pragma unroll
    for (int n = 0; n < 4; ++n) {
      int c = t + 256 * n;             // 1024 granules of 8 u16
      int d = c >> 3, g = c & 7;
      short8 vv = *(const short8*)(vt + (size_t)(h * HD_ + d) * S_ + j0 + g * 8);
      *(short8*)&svt[d][(g ^ (d & 7)) << 3] = vv;
    }
    __syncthreads();

    const bool diag = (jt == bx);

    // QK^T: per wave 16x64 scores, 4 col-frags
#pragma unroll
    for (int jf = 0; jf < 4; ++jf) {
      f32x4 s = (f32x4){0.f, 0.f, 0.f, 0.f};
#pragma unroll
      for (int ks = 0; ks < 4; ++ks) {
        int krow = jf * 16 + l15;
        int sw = (((ks * 4 + hi) ^ (krow & 15)) << 3);
        short8 kbh = *(const short8*)&skh[krow][sw];
        short8 kbl = *(const short8*)&skl[krow][sw];
        s = __builtin_amdgcn_mfma_f32_16x16x32_bf16(fqh[ks], kbh, s, 0, 0, 0);
        s = __builtin_amdgcn_mfma_f32_16x16x32_bf16(fqh[ks], kbl, s, 0, 0, 0);
        s = __builtin_amdgcn_mfma_f32_16x16x32_bf16(fql[ks], kbh, s, 0, 0, 0);
      }
      // mask + split + store: lane holds (q=hi*4+r, kcol=jf*16+l15)
#pragma unroll
      for (int r = 0; r < 4; ++r) {
        float val = s[r];
        int il = hi * 4 + r;           // q local in wave strip
        int jl = jf * 16 + l15;        // k local in 64-tile
        if (diag && (wv * 16 + il) < jl) val = 0.f;   // causal
        u16 hb, lb;
        split1(val, hb, lb);
        int swc = (((jl >> 3) ^ (il & 7)) << 3) + (jl & 7);
        ssc[wv][0][il][swc] = hb;
        ssc[wv][1][il][swc] = lb;
      }
    }

    // PV: yacc[dt] += scores(16x64) @ vT-tile(64x128)
#pragma unroll
    for (int ks = 0; ks < 2; ++ks) {
      int gA = ks * 4 + hi;
      short8 sah = *(const short8*)&ssc[wv][0][l15][(gA ^ (l15 & 7)) << 3];
      short8 sal = *(const short8*)&ssc[wv][1][l15][(gA ^ (l15 & 7)) << 3];
#pragma unroll
      for (int dt = 0; dt < 8; ++dt) {
        int d = dt * 16 + l15;
        short8 vb = *(const short8*)&svt[d][(gA ^ (d & 7)) << 3];
        yacc[dt] = __builtin_amdgcn_mfma_f32_16x16x32_bf16(sah, vb, yacc[dt], 0, 0, 0);
        yacc[dt] = __builtin_amdgcn_mfma_f32_16x16x32_bf16(sal, vb, yacc[dt], 0, 0, 0);
      }
    }
  }

  // epilogue: D col=l15 -> d, row=hi*4+r -> q; write y in-place over q
#pragma unroll
  for (int dt = 0; dt < 8; ++dt)
#pragma unroll
    for (int r = 0; r < 4; ++r)
      qy[(size_t)(i0 + wv * 16 + hi * 4 + r) * D_ + h * HD_ + dt * 16 + l15] =
          yacc[dt][r];
}

// ---------------------------------------------------------------------------
__global__ __launch_bounds__(256) void ln_gate(const float* __restrict__ y,
                                               const bf16* __restrict__ g,
                                               const void* __restrict__ lnw,
                                               const void* __restrict__ lnb,
                                               float* __restrict__ a) {
  const int row = blockIdx.x;
  const int t = threadIdx.x;
  const bool lF = is_f32(lnw);
  const float* yr = y + (size_t)row * D_;

  float v[8], s = 0.f, s2 = 0.f;
#pragma unroll
  for (int e = 0; e < 8; ++e) {
    v[e] = yr[t + 256 * e];
    s += v[e];
    s2 += v[e] * v[e];
  }
#pragma unroll
  for (int off = 32; off > 0; off >>= 1) {
    s += __shfl_down(s, off);
    s2 += __shfl_down(s2, off);
  }
  __shared__ float red[8];
  __shared__ float mv[2];
  if ((t & 63) == 0) { red[(t >> 6) * 2] = s; red[(t >> 6) * 2 + 1] = s2; }
  __syncthreads();
  if (t == 0) {
    float S1 = red[0] + red[2] + red[4] + red[6];
    float S2 = red[1] + red[3] + red[5] + red[7];
    float mu = S1 * (1.f / (float)D_);
    float var = S2 * (1.f / (float)D_) - mu * mu;
    mv[0] = mu;
    mv[1] = rsqrtf(var + 1e-5f);
  }
  __syncthreads();
  float mu = mv[0], rstd = mv[1];
#pragma unroll
  for (int e = 0; e < 8; ++e) {
    int col = t + 256 * e;
    float lw = lF ? ((const float*)lnw)[col] : (float)((const bf16*)lnw)[col];
    float lb = lF ? ((const float*)lnb)[col] : (float)((const bf16*)lnb)[col];
    float val = (v[e] - mu) * rstd * lw + lb;
    float gg = (float)g[(size_t)row * D_ + col];
    a[(size_t)row * D_ + col] = val * gg;
  }
}

// ---------------------------------------------------------------------------
extern "C" void kernel_launch(void* const* d_in, const int* in_sizes, int n_in,
                              void* d_out, int out_size, void* d_ws, size_t ws_size,
                              hipStream_t stream) {
  const void* x   = d_in[0];
  const void* wq  = d_in[1];
  const void* wk  = d_in[2];
  const void* wv  = d_in[3];
  const void* wg  = d_in[4];
  const void* wo  = d_in[5];
  const void* lnw = d_in[6];
  const void* lnb = d_in[7];

  char* ws = (char*)d_ws;
  float* q  = (float*)(ws);                  // 16 MiB fp32; becomes y in-place
  float* kk = (float*)(ws + (16ull << 20));  // 16 MiB fp32; becomes a
  bf16*  vt = (bf16*)(ws + (32ull << 20));   // 8 MiB bf16 vT[n][s]
  float* a  = kk;
  bf16*  g  = (bf16*)d_out;                  // staged in d_out[0,8M), dead
  float* out = (float*)d_out;                // OUTPUT IS FP32

  dim3 blk(256);
  dim3 gg(16, 16);
  gemm_mfma<<<gg, blk, 0, stream>>>((const float*)x, (const float*)wq, q,  0, 0, 0);
  gemm_mfma<<<gg, blk, 0, stream>>>((const float*)x, (const float*)wk, kk, 0, 0, 0);
  gemm_mfma<<<gg, blk, 0, stream>>>((const float*)x, (const float*)wv, vt, 0, 1, 1);
  gemm_mfma<<<gg, blk, 0, stream>>>((const float*)x, (const float*)wg, g,  1, 1, 0);
  attn_mfma<<<dim3(32, 16), blk, 0, stream>>>(q, kk, vt);
  ln_gate<<<dim3(2048), blk, 0, stream>>>(q /*=y*/, g, lnw, lnb, a);
  gemm_mfma<<<gg, blk, 0, stream>>>(a, (const float*)wo, out, 0, 0, 0);
}

// Round 3
// 585.215 us; speedup vs baseline: 6.9834x; 1.4139x over previous
//
#include <hip/hip_runtime.h>
#include <hip/hip_bf16.h>
#include <math.h>

// ROUND 10: GEMM LDS conflict fix + QKVG fusion.
// r9 counters: gemm_mfma = 5x131us (79% of wall), MfmaUtil 16%, HBM 8%,
// SQ_LDS_BANK_CONFLICT 8.4M/dispatch, grid 256 = 1 block/CU (no TLP).
// Changes: (1) LDS layout [128][64] u16, hi|lo packed per row (128B row =
// 32 banks), XOR-swizzled on 16B granules (phys = logical ^ (row&7)) ->
// conflict-free b128 frag reads, 2-way (free) staging writes; 80->64 KB.
// (2) Q/K/V/G projections fused into one grid(16,16,4) launch -> 2 blocks/CU,
// cross-block MFMA/stage overlap + L2 reuse of x panels.
// Numerics (split order, MFMA order) unchanged -> absmax should be
// bit-identical. attn_mfma / ln_gate unchanged from r9.
// Established: inputs fp32, output fp32, ws >= 40 MiB.
// ws: [0,16M) q fp32 -> y in-place; [16,32M) k fp32 -> a (reuse);
// [32,40M) vT bf16. g bf16 staged in d_out[0,8M), dead before final GEMM.

typedef __bf16 bf16;
typedef unsigned short u16;
typedef __attribute__((ext_vector_type(4))) float f32x4;
typedef __attribute__((ext_vector_type(8))) short short8;
typedef __attribute__((ext_vector_type(4))) short short4v;

#define S_ 2048
#define D_ 2048
#define H_ 16
#define HD_ 128
#define SCALE_ 0.08838834764831843f   // 128^-0.5

union BU { bf16 b; u16 u; };

__device__ __forceinline__ u16 bfbits(float f) { BU x; x.b = (bf16)f; return x.u; }

__device__ __forceinline__ void split1(float f, u16& h, u16& l) {
  unsigned int bits = __float_as_uint(f);
  h = (u16)(bits >> 16);                          // truncation split (exact)
  float hf = __uint_as_float(bits & 0xFFFF0000u);
  l = bfbits(f - hf);                             // RNE residual
}

__device__ __forceinline__ bool is_f32(const void* p) {
  const u16* xr = (const u16*)p;
  int cnt = 0;
  for (int i = 0; i < 128; ++i) {
    int e = (xr[2 * i] >> 7) & 0xFF;
    cnt += (e >= 100 && e <= 140) ? 1 : 0;
  }
  return cnt < 96;
}

// ---------------------------------------------------------------------------
// MFMA GEMM: C(2048,2048) = A @ W^T, split-bf16 3-product, 128x128 tile,
// BK=32. LDS per operand: [128][64] u16 rows = [hi(4 gran)|lo(4 gran)],
// physical granule = logical ^ (row&7)  -> conflict-free ds_read_b128.
// z-fused: blockIdx.z selects W/C/mode (QKVG in one launch).
// mode bits: 1=c_bf16, 2=vt(transposed bf16), 4=silu.
// ---------------------------------------------------------------------------
__device__ __forceinline__ void load8(const float* __restrict__ P,
    int base_row, int ko, int t, f32x4* r) {
#pragma unroll
  for (int n = 0; n < 2; ++n) {
    int id = t + 256 * n;
    int row = id >> 2, ch = id & 3;
    const float* p = P + (size_t)(base_row + row) * D_ + ko + ch * 8;
    r[2 * n]     = *(const f32x4*)p;
    r[2 * n + 1] = *(const f32x4*)(p + 4);
  }
}

__device__ __forceinline__ void swrite(const f32x4* __restrict__ r, int t,
                                       u16 (* __restrict__ dst)[64]) {
#pragma unroll
  for (int n = 0; n < 2; ++n) {
    int id = t + 256 * n;
    int row = id >> 2, ch = id & 3;
    short8 hh, ll;
#pragma unroll
    for (int e = 0; e < 8; ++e) {
      float f = (e < 4) ? r[2 * n][e] : r[2 * n + 1][e - 4];
      u16 hb, lb;
      split1(f, hb, lb);
      hh[e] = (short)hb;
      ll[e] = (short)lb;
    }
    const int m7 = row & 7;
    *(short8*)&dst[row][(ch ^ m7) * 8]     = hh;
    *(short8*)&dst[row][(ch ^ 4 ^ m7) * 8] = ll;
  }
}

__global__ __launch_bounds__(256, 2) void gemm_mfma(
    const float* __restrict__ A,
    const float* __restrict__ W0, const float* __restrict__ W1,
    const float* __restrict__ W2, const float* __restrict__ W3,
    void* __restrict__ C0, void* __restrict__ C1,
    void* __restrict__ C2, void* __restrict__ C3, int modes) {
  __shared__ __align__(16) u16 sA[2][128][64];
  __shared__ __align__(16) u16 sW[2][128][64];

  const int z = blockIdx.z;
  const float* W = (z == 0) ? W0 : (z == 1) ? W1 : (z == 2) ? W2 : W3;
  void* Cv       = (z == 0) ? C0 : (z == 1) ? C1 : (z == 2) ? C2 : C3;
  const int mode = (modes >> (4 * z)) & 15;

  const int t = threadIdx.x;
  const int lane = t & 63;
  const int wv = t >> 6;
  const int wr = (wv >> 1) * 64;
  const int wc = (wv & 1) * 64;
  const int r0 = blockIdx.y * 128;
  const int c0 = blockIdx.x * 128;

  const int l15 = lane & 15;
  const int q = lane >> 4;         // frag k-granule 0..3
  const int m7 = l15 & 7;          // frag row & 7 (wr,i*16 are mult of 16)
  const int gh = (q ^ m7) * 8;     // hi granule offset (u16)
  const int gl = (q ^ 4 ^ m7) * 8; // lo granule offset

  f32x4 ra[4], rw[4];
  f32x4 acc[4][4];
#pragma unroll
  for (int i = 0; i < 4; ++i)
#pragma unroll
    for (int j = 0; j < 4; ++j) acc[i][j] = (f32x4){0.f, 0.f, 0.f, 0.f};

  load8(A, r0, 0, t, ra);
  load8(W, c0, 0, t, rw);
  swrite(ra, t, sA[0]);
  swrite(rw, t, sW[0]);
  __syncthreads();

  for (int kt = 0; kt < D_ / 32; ++kt) {
    const int cur = kt & 1;
    const bool more = (kt + 1 < D_ / 32);
    if (more) {
      load8(A, r0, (kt + 1) * 32, t, ra);
      load8(W, c0, (kt + 1) * 32, t, rw);
    }

    short8 fah[4], fal[4], fbh[4], fbl[4];
#pragma unroll
    for (int i = 0; i < 4; ++i) {
      fah[i] = *(const short8*)&sA[cur][wr + i * 16 + l15][gh];
      fal[i] = *(const short8*)&sA[cur][wr + i * 16 + l15][gl];
      fbh[i] = *(const short8*)&sW[cur][wc + i * 16 + l15][gh];
      fbl[i] = *(const short8*)&sW[cur][wc + i * 16 + l15][gl];
    }
#pragma unroll
    for (int i = 0; i < 4; ++i)
#pragma unroll
      for (int j = 0; j < 4; ++j) {
        acc[i][j] = __builtin_amdgcn_mfma_f32_16x16x32_bf16(fah[i], fbh[j], acc[i][j], 0, 0, 0);
        acc[i][j] = __builtin_amdgcn_mfma_f32_16x16x32_bf16(fah[i], fbl[j], acc[i][j], 0, 0, 0);
        acc[i][j] = __builtin_amdgcn_mfma_f32_16x16x32_bf16(fal[i], fbh[j], acc[i][j], 0, 0, 0);
      }
    if (more) {
      swrite(ra, t, sA[cur ^ 1]);
      swrite(rw, t, sW[cur ^ 1]);
    }
    __syncthreads();
  }

  const int orow = (lane >> 4) * 4;   // C/D: col=lane&15, row=(lane>>4)*4+r
  if (mode & 2) {                      // vt: bf16 transposed vT[n][s]
#pragma unroll
    for (int i = 0; i < 4; ++i)
#pragma unroll
      for (int j = 0; j < 4; ++j) {
        short4v p;
#pragma unroll
        for (int r = 0; r < 4; ++r) p[r] = (short)bfbits(acc[i][j][r]);
        size_t n  = (size_t)(c0 + wc + j * 16 + l15);
        size_t s0 = (size_t)(r0 + wr + i * 16 + orow);
        *(short4v*)((bf16*)Cv + n * (size_t)S_ + s0) = p;
      }
  } else {
#pragma unroll
    for (int i = 0; i < 4; ++i)
#pragma unroll
      for (int j = 0; j < 4; ++j)
#pragma unroll
        for (int r = 0; r < 4; ++r) {
          float val = acc[i][j][r];
          if (mode & 4) val = val / (1.f + expf(-val));
          size_t idx = (size_t)(r0 + wr + i * 16 + orow + r) * D_ +
                       (c0 + wc + j * 16 + l15);
          if (mode & 1) ((bf16*)Cv)[idx] = (bf16)val;
          else          ((float*)Cv)[idx] = val;
        }
  }
}

// ---------------------------------------------------------------------------
// MFMA retention attention (r9, unchanged). Block = (64-row i-tile, head).
// ---------------------------------------------------------------------------
__global__ __launch_bounds__(256, 2) void attn_mfma(
    float* __restrict__ qy, const float* __restrict__ k,
    const bf16* __restrict__ vt) {
  const int h = blockIdx.y;
  const int bxx = blockIdx.x;
  const int bx = (bxx & 1) ? (31 - (bxx >> 1)) : (bxx >> 1);
  const int i0 = bx * 64;
  const int t = threadIdx.x;
  const int lane = t & 63;
  const int wv = t >> 6;
  const int l15 = lane & 15;
  const int hi = lane >> 4;

  __shared__ __align__(16) u16 skh[64][128];
  __shared__ __align__(16) u16 skl[64][128];
  __shared__ __align__(16) u16 svt[128][64];
  __shared__ __align__(16) u16 ssc[4][2][16][64];

  const double l1 = -3.4657359027997265;
  const double l2 = -6.238324625039508;
  const float gam = (float)(1.0 - exp(l1 + (double)h * ((l2 - l1) / 15.0)));
  const float log2g = log2f(gam);

  short8 fqh[4], fql[4];
  {
    const float qs = SCALE_ * exp2f((float)(wv * 16 + l15) * log2g);
    const float* qrow = qy + (size_t)(i0 + wv * 16 + l15) * D_ + h * HD_;
#pragma unroll
    for (int ks = 0; ks < 4; ++ks) {
      f32x4 a = *(const f32x4*)(qrow + ks * 32 + hi * 8);
      f32x4 b = *(const f32x4*)(qrow + ks * 32 + hi * 8 + 4);
      short8 hh, ll;
#pragma unroll
      for (int e = 0; e < 8; ++e) {
        float f = (e < 4 ? a[e] : b[e - 4]) * qs;
        u16 hb, lb;
        split1(f, hb, lb);
        hh[e] = (short)hb;
        ll[e] = (short)lb;
      }
      fqh[ks] = hh;
      fql[ks] = ll;
    }
  }

  f32x4 yacc[8];
#pragma unroll
  for (int dt = 0; dt < 8; ++dt) yacc[dt] = (f32x4){0.f, 0.f, 0.f, 0.f};

  for (int jt = 0; jt <= bx; ++jt) {
    const int j0 = jt * 64;
    __syncthreads();

#pragma unroll
    for (int n = 0; n < 8; ++n) {
      int id = t + 256 * n;
      int row = id >> 5;
      int c4 = (id & 31) * 4;
      float ksc = exp2f((float)(i0 - j0 - row) * log2g);
      f32x4 kv = *(const f32x4*)(k + (size_t)(j0 + row) * D_ + h * HD_ + c4);
      short4v hh, ll;
#pragma unroll
      for (int e = 0; e < 4; ++e) {
        u16 hb, lb;
        split1(kv[e] * ksc, hb, lb);
        hh[e] = (short)hb;
        ll[e] = (short)lb;
      }
      int sw = (((c4 >> 3) ^ (row & 15)) << 3) + (c4 & 7);
      *(short4v*)&skh[row][sw] = hh;
      *(short4v*)&skl[row][sw] = ll;
    }
#pragma unroll
    for (int n = 0; n < 4; ++n) {
      int c = t + 256 * n;
      int d = c >> 3, g = c & 7;
      short8 vv = *(const short8*)(vt + (size_t)(h * HD_ + d) * S_ + j0 + g * 8);
      *(short8*)&svt[d][(g ^ (d & 7)) << 3] = vv;
    }
    __syncthreads();

    const bool diag = (jt == bx);

#pragma unroll
    for (int jf = 0; jf < 4; ++jf) {
      f32x4 s = (f32x4){0.f, 0.f, 0.f, 0.f};
#pragma unroll
      for (int ks = 0; ks < 4; ++ks) {
        int krow = jf * 16 + l15;
        int sw = (((ks * 4 + hi) ^ (krow & 15)) << 3);
        short8 kbh = *(const short8*)&skh[krow][sw];
        short8 kbl = *(const short8*)&skl[krow][sw];
        s = __builtin_amdgcn_mfma_f32_16x16x32_bf16(fqh[ks], kbh, s, 0, 0, 0);
        s = __builtin_amdgcn_mfma_f32_16x16x32_bf16(fqh[ks], kbl, s, 0, 0, 0);
        s = __builtin_amdgcn_mfma_f32_16x16x32_bf16(fql[ks], kbh, s, 0, 0, 0);
      }
#pragma unroll
      for (int r = 0; r < 4; ++r) {
        float val = s[r];
        int il = hi * 4 + r;
        int jl = jf * 16 + l15;
        if (diag && (wv * 16 + il) < jl) val = 0.f;
        u16 hb, lb;
        split1(val, hb, lb);
        int swc = (((jl >> 3) ^ (il & 7)) << 3) + (jl & 7);
        ssc[wv][0][il][swc] = hb;
        ssc[wv][1][il][swc] = lb;
      }
    }

#pragma unroll
    for (int ks = 0; ks < 2; ++ks) {
      int gA = ks * 4 + hi;
      short8 sah = *(const short8*)&ssc[wv][0][l15][(gA ^ (l15 & 7)) << 3];
      short8 sal = *(const short8*)&ssc[wv][1][l15][(gA ^ (l15 & 7)) << 3];
#pragma unroll
      for (int dt = 0; dt < 8; ++dt) {
        int d = dt * 16 + l15;
        short8 vb = *(const short8*)&svt[d][(gA ^ (d & 7)) << 3];
        yacc[dt] = __builtin_amdgcn_mfma_f32_16x16x32_bf16(sah, vb, yacc[dt], 0, 0, 0);
        yacc[dt] = __builtin_amdgcn_mfma_f32_16x16x32_bf16(sal, vb, yacc[dt], 0, 0, 0);
      }
    }
  }

#pragma unroll
  for (int dt = 0; dt < 8; ++dt)
#pragma unroll
    for (int r = 0; r < 4; ++r)
      qy[(size_t)(i0 + wv * 16 + hi * 4 + r) * D_ + h * HD_ + dt * 16 + l15] =
          yacc[dt][r];
}

// ---------------------------------------------------------------------------
__global__ __launch_bounds__(256) void ln_gate(const float* __restrict__ y,
                                               const bf16* __restrict__ g,
                                               const void* __restrict__ lnw,
                                               const void* __restrict__ lnb,
                                               float* __restrict__ a) {
  const int row = blockIdx.x;
  const int t = threadIdx.x;
  const bool lF = is_f32(lnw);
  const float* yr = y + (size_t)row * D_;

  float v[8], s = 0.f, s2 = 0.f;
#pragma unroll
  for (int e = 0; e < 8; ++e) {
    v[e] = yr[t + 256 * e];
    s += v[e];
    s2 += v[e] * v[e];
  }
#pragma unroll
  for (int off = 32; off > 0; off >>= 1) {
    s += __shfl_down(s, off);
    s2 += __shfl_down(s2, off);
  }
  __shared__ float red[8];
  __shared__ float mv[2];
  if ((t & 63) == 0) { red[(t >> 6) * 2] = s; red[(t >> 6) * 2 + 1] = s2; }
  __syncthreads();
  if (t == 0) {
    float S1 = red[0] + red[2] + red[4] + red[6];
    float S2 = red[1] + red[3] + red[5] + red[7];
    float mu = S1 * (1.f / (float)D_);
    float var = S2 * (1.f / (float)D_) - mu * mu;
    mv[0] = mu;
    mv[1] = rsqrtf(var + 1e-5f);
  }
  __syncthreads();
  float mu = mv[0], rstd = mv[1];
#pragma unroll
  for (int e = 0; e < 8; ++e) {
    int col = t + 256 * e;
    float lw = lF ? ((const float*)lnw)[col] : (float)((const bf16*)lnw)[col];
    float lb = lF ? ((const float*)lnb)[col] : (float)((const bf16*)lnb)[col];
    float val = (v[e] - mu) * rstd * lw + lb;
    float gg = (float)g[(size_t)row * D_ + col];
    a[(size_t)row * D_ + col] = val * gg;
  }
}

// ---------------------------------------------------------------------------
extern "C" void kernel_launch(void* const* d_in, const int* in_sizes, int n_in,
                              void* d_out, int out_size, void* d_ws, size_t ws_size,
                              hipStream_t stream) {
  const float* x   = (const float*)d_in[0];
  const float* wq  = (const float*)d_in[1];
  const float* wk  = (const float*)d_in[2];
  const float* wv  = (const float*)d_in[3];
  const float* wg  = (const float*)d_in[4];
  const float* wo  = (const float*)d_in[5];
  const void* lnw = d_in[6];
  const void* lnb = d_in[7];

  char* ws = (char*)d_ws;
  float* q  = (float*)(ws);                  // 16 MiB fp32; becomes y in-place
  float* kk = (float*)(ws + (16ull << 20));  // 16 MiB fp32; becomes a
  bf16*  vt = (bf16*)(ws + (32ull << 20));   // 8 MiB bf16 vT[n][s]
  float* a  = kk;
  bf16*  g  = (bf16*)d_out;                  // staged in d_out[0,8M), dead
  float* out = (float*)d_out;                // OUTPUT IS FP32

  dim3 blk(256);
  // fused QKVG: z0=q(fp32), z1=k(fp32), z2=vT(bf16 transposed), z3=g(silu,bf16)
  // mode bits: 1=bf16, 2=vt, 4=silu  -> modes nibble per z: 0,0,2,5
  gemm_mfma<<<dim3(16, 16, 4), blk, 0, stream>>>(
      x, wq, wk, wv, wg, q, kk, vt, g, 0x5200);
  attn_mfma<<<dim3(32, 16), blk, 0, stream>>>(q, kk, vt);
  ln_gate<<<dim3(2048), blk, 0, stream>>>(q /*=y*/, g, lnw, lnb, a);
  // wo GEMM: z=0 only, fp32 out
  gemm_mfma<<<dim3(16, 16, 1), blk, 0, stream>>>(
      a, wo, wo, wo, wo, out, out, out, out, 0x0);
}

// Round 4
// 577.391 us; speedup vs baseline: 7.0780x; 1.0136x over previous
//
#include <hip/hip_runtime.h>
#include <hip/hip_bf16.h>
#include <hip/hip_fp16.h>
#include <math.h>

// ROUND 11: bf16 3-product -> fp16 2-product everywhere + write-conflict-free
// LDS swizzles.
// Evidence: absmax bit-identical 0.015625 since the r7 fp32 oracle ->
// dominated by 8-bit bf16 v/g staging, NOT GEMM precision. So: fp16 (11-bit)
// fabric at same MFMA rate. GEMM: A single fp16, W split fp16 hi+lo ->
// C = A*Wh + A*Wl (2 products; error ~2^-11 rel ~ 5e-4, 30x below the old
// dominant term which itself improves 8->11 bit). Attn: QK 2-product
// (q single, k split), PV 1-product (scores fp16, v fp16).
// LDS: A [2][128][64] hlf BK=64 (staged every other step), W [2][128][64]
// hlf BK=32 hi(g0-3)|lo(g4-7); granule swz pg = g ^ (row&7); staging
// assignment row=t>>1 puts rows 0..7 in each 16-lane phase -> writes span
// all 8 granules (r10's write conflicts: 16-lane phase spanned only half
// the banks). Per block-K32: LDS 72 KB (was 96), MFMA 32/wave (was 48),
// no A-split VALU.
// Established: inputs fp32, output fp32, ws >= 40 MiB.
// ws: [0,16M) q fp32 -> y in-place; [16,32M) k fp32 -> a (reuse);
// [32,40M) vT fp16. g fp16 staged in d_out[0,8M), dead before final GEMM.

typedef _Float16 hlf;
typedef unsigned short u16;
typedef __attribute__((ext_vector_type(4))) float f32x4;
typedef __attribute__((ext_vector_type(8))) _Float16 hlf8;
typedef __attribute__((ext_vector_type(4))) _Float16 hlf4;

#define S_ 2048
#define D_ 2048
#define H_ 16
#define HD_ 128
#define SCALE_ 0.08838834764831843f   // 128^-0.5

__device__ __forceinline__ void splitH(float f, hlf& h, hlf& l) {
  h = (hlf)f;                 // RNE to fp16
  l = (hlf)(f - (float)h);    // residual
}

__device__ __forceinline__ bool is_f32(const void* p) {
  const u16* xr = (const u16*)p;
  int cnt = 0;
  for (int i = 0; i < 128; ++i) {
    int e = (xr[2 * i] >> 7) & 0xFF;
    cnt += (e >= 100 && e <= 140) ? 1 : 0;
  }
  return cnt < 96;
}

// ---------------------------------------------------------------------------
// MFMA GEMM: C(2048,2048) = A @ W^T. A single fp16, W split fp16 hi/lo.
// 128x128 tile, 4 waves (2x2) of 64x64. A: BK=64 double-buffered; W: BK=32
// double-buffered. z-fused QKVG. mode bits: 1=fp16 out, 2=transposed, 4=silu.
// ---------------------------------------------------------------------------
__global__ __launch_bounds__(256, 2) void gemm_mfma(
    const float* __restrict__ A,
    const float* __restrict__ W0, const float* __restrict__ W1,
    const float* __restrict__ W2, const float* __restrict__ W3,
    void* __restrict__ C0, void* __restrict__ C1,
    void* __restrict__ C2, void* __restrict__ C3, int modes) {
  __shared__ __align__(16) hlf sA[2][128][64];
  __shared__ __align__(16) hlf sW[2][128][64];

  const int z = blockIdx.z;
  const float* W = (z == 0) ? W0 : (z == 1) ? W1 : (z == 2) ? W2 : W3;
  void* Cv       = (z == 0) ? C0 : (z == 1) ? C1 : (z == 2) ? C2 : C3;
  const int mode = (modes >> (4 * z)) & 15;

  const int t = threadIdx.x;
  const int lane = t & 63;
  const int wv = t >> 6;
  const int wr = (wv >> 1) * 64;
  const int wc = (wv & 1) * 64;
  const int r0 = blockIdx.y * 128;
  const int c0 = blockIdx.x * 128;

  const int srow = t >> 1;     // staging row 0..127
  const int kh = t & 1;        // staging k-half
  const int sm7 = srow & 7;

  const int l15 = lane & 15;
  const int q = lane >> 4;     // frag k-chunk within 32-k window
  const int m7 = l15 & 7;

  f32x4 regA[8], regW[4];
  f32x4 acc[4][4];
#pragma unroll
  for (int i = 0; i < 4; ++i)
#pragma unroll
    for (int j = 0; j < 4; ++j) acc[i][j] = (f32x4){0.f, 0.f, 0.f, 0.f};

  const float* arow = A + (size_t)(r0 + srow) * D_;
  const float* wrow = W + (size_t)(c0 + srow) * D_;

  // ---- staging helpers (inlined via lambdas) ----
  auto loadA = [&](int ab) {
    const float* p = arow + ab * 64 + kh * 32;
#pragma unroll
    for (int n = 0; n < 8; ++n) regA[n] = *(const f32x4*)(p + n * 4);
  };
  auto writeA = [&](int buf) {
#pragma unroll
    for (int j = 0; j < 4; ++j) {
      hlf8 hv;
#pragma unroll
      for (int e = 0; e < 8; ++e) {
        float f = (e < 4) ? regA[2 * j][e] : regA[2 * j + 1][e - 4];
        hv[e] = (hlf)f;
      }
      *(hlf8*)&sA[buf][srow][(((kh * 4 + j) ^ sm7)) * 8] = hv;
    }
  };
  auto loadW = [&](int kt) {
    const float* p = wrow + kt * 32 + kh * 16;
#pragma unroll
    for (int n = 0; n < 4; ++n) regW[n] = *(const f32x4*)(p + n * 4);
  };
  auto writeW = [&](int buf) {
#pragma unroll
    for (int j = 0; j < 2; ++j) {
      hlf8 hv, lv;
#pragma unroll
      for (int e = 0; e < 8; ++e) {
        float f = (e < 4) ? regW[2 * j][e] : regW[2 * j + 1][e - 4];
        hlf hb, lb;
        splitH(f, hb, lb);
        hv[e] = hb;
        lv[e] = lb;
      }
      *(hlf8*)&sW[buf][srow][(((kh * 2 + j) ^ sm7)) * 8] = hv;
      *(hlf8*)&sW[buf][srow][(((4 + kh * 2 + j) ^ sm7)) * 8] = lv;
    }
  };

  // prologue
  loadA(0);
  writeA(0);
  loadW(0);
  writeW(0);
  __syncthreads();

  for (int kt = 0; kt < 64; ++kt) {
    const int abuf = (kt >> 1) & 1;
    const int wbuf = kt & 1;
    const int s = kt & 1;

    if (kt + 1 < 64) loadW(kt + 1);
    if ((kt & 1) == 0 && kt + 2 < 64) loadA((kt + 2) >> 1);

    hlf8 fa[4], fh[4], fl[4];
#pragma unroll
    for (int i = 0; i < 4; ++i)
      fa[i] = *(const hlf8*)&sA[abuf][wr + i * 16 + l15][(((4 * s + q) ^ m7)) * 8];
#pragma unroll
    for (int j = 0; j < 4; ++j) {
      fh[j] = *(const hlf8*)&sW[wbuf][wc + j * 16 + l15][((q ^ m7)) * 8];
      fl[j] = *(const hlf8*)&sW[wbuf][wc + j * 16 + l15][(((4 | q) ^ m7)) * 8];
    }
#pragma unroll
    for (int i = 0; i < 4; ++i)
#pragma unroll
      for (int j = 0; j < 4; ++j) {
        acc[i][j] = __builtin_amdgcn_mfma_f32_16x16x32_f16(fa[i], fh[j], acc[i][j], 0, 0, 0);
        acc[i][j] = __builtin_amdgcn_mfma_f32_16x16x32_f16(fa[i], fl[j], acc[i][j], 0, 0, 0);
      }

    if (kt + 1 < 64) writeW((kt + 1) & 1);
    if ((kt & 1) == 1 && kt + 1 < 64) writeA(((kt + 1) >> 1) & 1);
    __syncthreads();
  }

  const int orow = (lane >> 4) * 4;   // C/D: col=lane&15, row=(lane>>4)*4+r
  if (mode & 2) {                      // transposed fp16 vT[n][s]
#pragma unroll
    for (int i = 0; i < 4; ++i)
#pragma unroll
      for (int j = 0; j < 4; ++j) {
        hlf4 p;
#pragma unroll
        for (int r = 0; r < 4; ++r) p[r] = (hlf)acc[i][j][r];
        size_t n  = (size_t)(c0 + wc + j * 16 + l15);
        size_t s0 = (size_t)(r0 + wr + i * 16 + orow);
        *(hlf4*)((hlf*)Cv + n * (size_t)S_ + s0) = p;
      }
  } else {
#pragma unroll
    for (int i = 0; i < 4; ++i)
#pragma unroll
      for (int j = 0; j < 4; ++j)
#pragma unroll
        for (int r = 0; r < 4; ++r) {
          float val = acc[i][j][r];
          if (mode & 4) val = val / (1.f + expf(-val));
          size_t idx = (size_t)(r0 + wr + i * 16 + orow + r) * D_ +
                       (c0 + wc + j * 16 + l15);
          if (mode & 1) ((hlf*)Cv)[idx] = (hlf)val;
          else          ((float*)Cv)[idx] = val;
        }
  }
}

// ---------------------------------------------------------------------------
// MFMA retention attention, fp16. Block = (64-row i-tile, head), 4 waves.
// q single fp16 in regs (scaled); k split fp16 hi/lo (scaled); QK 2-product;
// scores single fp16 -> PV 1-product with fp16 vT.
// ---------------------------------------------------------------------------
__global__ __launch_bounds__(256, 2) void attn_mfma(
    float* __restrict__ qy, const float* __restrict__ k,
    const hlf* __restrict__ vt) {
  const int h = blockIdx.y;
  const int bxx = blockIdx.x;
  const int bx = (bxx & 1) ? (31 - (bxx >> 1)) : (bxx >> 1);  // pair long+short
  const int i0 = bx * 64;
  const int t = threadIdx.x;
  const int lane = t & 63;
  const int wv = t >> 6;
  const int l15 = lane & 15;
  const int hi = lane >> 4;

  __shared__ __align__(16) hlf skh[64][128];   // k hi, swz g^(row&15)
  __shared__ __align__(16) hlf skl[64][128];   // k lo
  __shared__ __align__(16) hlf svt[128][64];   // vT, swz g^(row&7)
  __shared__ __align__(16) hlf ssc[4][16][64]; // scores per wave, fp16

  const double l1 = -3.4657359027997265;
  const double l2 = -6.238324625039508;
  const float gam = (float)(1.0 - exp(l1 + (double)h * ((l2 - l1) / 15.0)));
  const float log2g = log2f(gam);

  // q fragments: A layout row=lane&15, k=(lane>>4)*8+e; single fp16, scaled
  hlf8 fq[4];
  {
    const float qs = SCALE_ * exp2f((float)(wv * 16 + l15) * log2g);
    const float* qrow = qy + (size_t)(i0 + wv * 16 + l15) * D_ + h * HD_;
#pragma unroll
    for (int ks = 0; ks < 4; ++ks) {
      f32x4 a = *(const f32x4*)(qrow + ks * 32 + hi * 8);
      f32x4 b = *(const f32x4*)(qrow + ks * 32 + hi * 8 + 4);
      hlf8 hh;
#pragma unroll
      for (int e = 0; e < 8; ++e) {
        float f = (e < 4 ? a[e] : b[e - 4]) * qs;
        hh[e] = (hlf)f;
      }
      fq[ks] = hh;
    }
  }

  f32x4 yacc[8];
#pragma unroll
  for (int dt = 0; dt < 8; ++dt) yacc[dt] = (f32x4){0.f, 0.f, 0.f, 0.f};

  for (int jt = 0; jt <= bx; ++jt) {
    const int j0 = jt * 64;
    __syncthreads();   // prev iteration's frag reads done before restage

    // stage k: 64 rows x 128 d fp32 -> split fp16, scaled gamma^(i0-j)
#pragma unroll
    for (int n = 0; n < 8; ++n) {
      int id = t + 256 * n;
      int row = id >> 5;
      int c4 = (id & 31) * 4;
      float ksc = exp2f((float)(i0 - j0 - row) * log2g);
      f32x4 kv = *(const f32x4*)(k + (size_t)(j0 + row) * D_ + h * HD_ + c4);
      hlf4 hh, ll;
#pragma unroll
      for (int e = 0; e < 4; ++e) {
        hlf hb, lb;
        splitH(kv[e] * ksc, hb, lb);
        hh[e] = hb;
        ll[e] = lb;
      }
      int sw = (((c4 >> 3) ^ (row & 15)) << 3) + (c4 & 7);
      *(hlf4*)&skh[row][sw] = hh;
      *(hlf4*)&skl[row][sw] = ll;
    }
    // stage vT: 128 rows(d) x 64 cols(s) fp16
#pragma unroll
    for (int n = 0; n < 4; ++n) {
      int c = t + 256 * n;
      int d = c >> 3, g = c & 7;
      hlf8 vv = *(const hlf8*)(vt + (size_t)(h * HD_ + d) * S_ + j0 + g * 8);
      *(hlf8*)&svt[d][(g ^ (d & 7)) << 3] = vv;
    }
    __syncthreads();

    const bool diag = (jt == bx);

    // QK^T: per wave 16x64 scores, 2-product
#pragma unroll
    for (int jf = 0; jf < 4; ++jf) {
      f32x4 s = (f32x4){0.f, 0.f, 0.f, 0.f};
#pragma unroll
      for (int ks = 0; ks < 4; ++ks) {
        int krow = jf * 16 + l15;
        int sw = (((ks * 4 + hi) ^ (krow & 15)) << 3);
        hlf8 kbh = *(const hlf8*)&skh[krow][sw];
        hlf8 kbl = *(const hlf8*)&skl[krow][sw];
        s = __builtin_amdgcn_mfma_f32_16x16x32_f16(fq[ks], kbh, s, 0, 0, 0);
        s = __builtin_amdgcn_mfma_f32_16x16x32_f16(fq[ks], kbl, s, 0, 0, 0);
      }
      // mask + store: lane holds (q=hi*4+r, kcol=jf*16+l15)
#pragma unroll
      for (int r = 0; r < 4; ++r) {
        float val = s[r];
        int il = hi * 4 + r;
        int jl = jf * 16 + l15;
        if (diag && (wv * 16 + il) < jl) val = 0.f;
        int swc = (((jl >> 3) ^ (il & 7)) << 3) + (jl & 7);
        ssc[wv][il][swc] = (hlf)val;
      }
    }

    // PV: yacc[dt] += scores(16x64) @ vT-tile(64x128), 1-product
#pragma unroll
    for (int ks = 0; ks < 2; ++ks) {
      int gA = ks * 4 + hi;
      hlf8 sa = *(const hlf8*)&ssc[wv][l15][(gA ^ (l15 & 7)) << 3];
#pragma unroll
      for (int dt = 0; dt < 8; ++dt) {
        int d = dt * 16 + l15;
        hlf8 vb = *(const hlf8*)&svt[d][(gA ^ (d & 7)) << 3];
        yacc[dt] = __builtin_amdgcn_mfma_f32_16x16x32_f16(sa, vb, yacc[dt], 0, 0, 0);
      }
    }
  }

  // epilogue: D col=l15 -> d, row=hi*4+r -> q; write y in-place over q
#pragma unroll
  for (int dt = 0; dt < 8; ++dt)
#pragma unroll
    for (int r = 0; r < 4; ++r)
      qy[(size_t)(i0 + wv * 16 + hi * 4 + r) * D_ + h * HD_ + dt * 16 + l15] =
          yacc[dt][r];
}

// ---------------------------------------------------------------------------
__global__ __launch_bounds__(256) void ln_gate(const float* __restrict__ y,
                                               const hlf* __restrict__ g,
                                               const void* __restrict__ lnw,
                                               const void* __restrict__ lnb,
                                               float* __restrict__ a) {
  const int row = blockIdx.x;
  const int t = threadIdx.x;
  const bool lF = is_f32(lnw);
  const float* yr = y + (size_t)row * D_;

  float v[8], s = 0.f, s2 = 0.f;
#pragma unroll
  for (int e = 0; e < 8; ++e) {
    v[e] = yr[t + 256 * e];
    s += v[e];
    s2 += v[e] * v[e];
  }
#pragma unroll
  for (int off = 32; off > 0; off >>= 1) {
    s += __shfl_down(s, off);
    s2 += __shfl_down(s2, off);
  }
  __shared__ float red[8];
  __shared__ float mv[2];
  if ((t & 63) == 0) { red[(t >> 6) * 2] = s; red[(t >> 6) * 2 + 1] = s2; }
  __syncthreads();
  if (t == 0) {
    float S1 = red[0] + red[2] + red[4] + red[6];
    float S2 = red[1] + red[3] + red[5] + red[7];
    float mu = S1 * (1.f / (float)D_);
    float var = S2 * (1.f / (float)D_) - mu * mu;
    mv[0] = mu;
    mv[1] = rsqrtf(var + 1e-5f);
  }
  __syncthreads();
  float mu = mv[0], rstd = mv[1];
#pragma unroll
  for (int e = 0; e < 8; ++e) {
    int col = t + 256 * e;
    float lw = lF ? ((const float*)lnw)[col] : (float)((const __bf16*)lnw)[col];
    float lb = lF ? ((const float*)lnb)[col] : (float)((const __bf16*)lnb)[col];
    float val = (v[e] - mu) * rstd * lw + lb;
    float gg = (float)g[(size_t)row * D_ + col];
    a[(size_t)row * D_ + col] = val * gg;
  }
}

// ---------------------------------------------------------------------------
extern "C" void kernel_launch(void* const* d_in, const int* in_sizes, int n_in,
                              void* d_out, int out_size, void* d_ws, size_t ws_size,
                              hipStream_t stream) {
  const float* x   = (const float*)d_in[0];
  const float* wq  = (const float*)d_in[1];
  const float* wk  = (const float*)d_in[2];
  const float* wv  = (const float*)d_in[3];
  const float* wg  = (const float*)d_in[4];
  const float* wo  = (const float*)d_in[5];
  const void* lnw = d_in[6];
  const void* lnb = d_in[7];

  char* ws = (char*)d_ws;
  float* q  = (float*)(ws);                  // 16 MiB fp32; becomes y in-place
  float* kk = (float*)(ws + (16ull << 20));  // 16 MiB fp32; becomes a
  hlf*   vt = (hlf*)(ws + (32ull << 20));    // 8 MiB fp16 vT[n][s]
  float* a  = kk;
  hlf*   g  = (hlf*)d_out;                   // staged in d_out[0,8M), dead
  float* out = (float*)d_out;                // OUTPUT IS FP32

  dim3 blk(256);
  // fused QKVG: z0=q(fp32), z1=k(fp32), z2=vT(fp16 transposed), z3=g(silu,fp16)
  // mode bits: 1=fp16 out, 2=transposed, 4=silu -> nibbles: 0,0,3,5
  gemm_mfma<<<dim3(16, 16, 4), blk, 0, stream>>>(
      x, wq, wk, wv, wg, q, kk, vt, g, 0x5300);
  attn_mfma<<<dim3(32, 16), blk, 0, stream>>>(q, kk, vt);
  ln_gate<<<dim3(2048), blk, 0, stream>>>(q /*=y*/, g, lnw, lnb, a);
  // wo GEMM: z=0 only, fp32 out
  gemm_mfma<<<dim3(16, 16, 1), blk, 0, stream>>>(
      a, wo, wo, wo, wo, out, out, out, out, 0x0);
}